// Round 13
// baseline (242.893 us; speedup 1.0000x reference)
//
#include <hip/hip_runtime.h>
#include <hip/hip_bf16.h>
#include <stdint.h>

#define B_ 4
#define T_ 8
#define N_ 4096
#define F_ 32
#define BT_ (B_*T_)
#define ROWS_ (B_*N_)
#define CAP_ 128
#define EPS_ 1e-5f
#define NELEM_ (B_*T_*N_*F_)

// ---- workspace layout (float offsets) ----
#define WS_BNP    0                       // 256 * 64 per-block BN partials (no atomics)
#define WS_ROWSUM 16384                   // 4096
#define WS_DEG    (WS_ROWSUM + 4096)      // 4096 (int)
#define WS_FRG    (WS_DEG + 4096)         // 52 frags * 64 lanes * 4 dwords
#define WS_PAIR   (WS_FRG + 52*256)       // 4096*CAP_*2  (idx*F_ as float-bits, val)
#define WS_XA     (WS_PAIR + 4096*CAP_*2) // BT_*N_*F_

typedef float v4f __attribute__((ext_vector_type(4)));
typedef _Float16 half8 __attribute__((ext_vector_type(8)));
union HU { uint32_t u[4]; half8 v; };

__device__ inline float sigm_f(float x) {
  return __builtin_amdgcn_rcpf(1.0f + __expf(-x));
}
__device__ inline uint32_t f16pair(float a, float b) {
  union { _Float16 h; unsigned short s; } x, y;
  x.h = (_Float16)a; y.h = (_Float16)b;
  return (uint32_t)x.s | ((uint32_t)y.s << 16);
}
__device__ inline unsigned short f2h(float a) {
  union { _Float16 h; unsigned short s; } u; u.h = (_Float16)a; return u.s;
}
__device__ inline float h2f(unsigned short s) {
  union { _Float16 h; unsigned short s; } u; u.s = s; return (float)u.h;
}
__device__ inline void sp2(float a0, float a1, uint32_t& hi, uint32_t& lo) {
  _Float16 h0 = (_Float16)a0, h1 = (_Float16)a1;
  float r0 = a0 - (float)h0, r1 = a1 - (float)h1;
  union { _Float16 h; unsigned short s; } u0, u1, v0, v1;
  u0.h = h0; u1.h = h1; v0.h = (_Float16)r0; v1.h = (_Float16)r1;
  hi = (uint32_t)u0.s | ((uint32_t)u1.s << 16);
  lo = (uint32_t)v0.s | ((uint32_t)v1.s << 16);
}

// ---- K1: CSR build, 2 rows/block (blocks 0..2047) + BN partials (2048..2303) ----
__global__ void __launch_bounds__(256)
k_pre(const float* __restrict__ x, const float* __restrict__ A, float* __restrict__ ws) {
  if (blockIdx.x < 2048) {
    int m0 = blockIdx.x * 2;
    __shared__ int cnt[2];
    __shared__ float wsum[4][2];
    if (threadIdx.x < 2) cnt[threadIdx.x] = 0;
    __syncthreads();
    int* deg = (int*)&ws[WS_DEG];
    float2* pair = (float2*)&ws[WS_PAIR];
    const float4* A4 = (const float4*)(A + (size_t)m0 * N_);
    float4 av4[8];
#pragma unroll
    for (int r = 0; r < 2; r++)
#pragma unroll
      for (int i = 0; i < 4; i++) av4[r * 4 + i] = A4[r * 1024 + threadIdx.x + 256 * i];
    float lsum[2] = {0.f, 0.f};
#pragma unroll
    for (int r = 0; r < 2; r++)
#pragma unroll
      for (int i = 0; i < 4; i++) {
        float av[4] = {av4[r*4+i].x, av4[r*4+i].y, av4[r*4+i].z, av4[r*4+i].w};
        int nb4 = (threadIdx.x + 256 * i) * 4;
#pragma unroll
        for (int e = 0; e < 4; e++) {
          float a = av[e];
          if (a != 0.0f) {
            int p = atomicAdd(&cnt[r], 1);
            if (p < CAP_) pair[(size_t)(m0 + r) * CAP_ + p] = make_float2(__int_as_float((nb4 + e) * F_), a);
            lsum[r] += a;
          }
        }
      }
#pragma unroll
    for (int r = 0; r < 2; r++) {
      float s = lsum[r];
#pragma unroll
      for (int off = 32; off > 0; off >>= 1) s += __shfl_xor(s, off, 64);
      if ((threadIdx.x & 63) == 0) wsum[threadIdx.x >> 6][r] = s;
    }
    __syncthreads();                     // cnt + wsum final
#pragma unroll
    for (int r = 0; r < 2; r++) {
      int c = cnt[r];
      for (int p = c + threadIdx.x; p < 68; p += 256)   // zero-fill incl. prefetch pad
        pair[(size_t)(m0 + r) * CAP_ + p] = make_float2(__int_as_float(0), 0.0f);
    }
    if (threadIdx.x < 2) {
      int r = threadIdx.x;
      deg[m0 + r] = min(cnt[r], CAP_);
      ws[WS_ROWSUM + m0 + r] = wsum[0][r] + wsum[1][r] + wsum[2][r] + wsum[3][r];
    }
  } else {
    int bnb = blockIdx.x - 2048;
    const float4* x4 = (const float4*)x;
    int tid = bnb * 256 + threadIdx.x;
    float s[4] = {0,0,0,0}, s2[4] = {0,0,0,0};
    for (int i = tid; i < NELEM_ / 4; i += 256 * 256) {
      float4 v = x4[i];
      s[0] += v.x; s2[0] += v.x * v.x;
      s[1] += v.y; s2[1] += v.y * v.y;
      s[2] += v.z; s2[2] += v.z * v.z;
      s[3] += v.w; s2[3] += v.w * v.w;
    }
    __shared__ float ls[256][4], ls2[256][4];
#pragma unroll
    for (int r = 0; r < 4; r++) { ls[threadIdx.x][r] = s[r]; ls2[threadIdx.x][r] = s2[r]; }
    __syncthreads();
    int t = threadIdx.x;
    if (t < 32) {                       // channel c = 4*(q&7)+r
      int g = t >> 2, r = t & 3;
      float a = 0.f;
      for (int q = g; q < 256; q += 8) a += ls[q][r];
      ws[WS_BNP + bnb * 64 + t] = a;
    } else if (t < 64) {
      int cch = t - 32;
      int g = cch >> 2, r = cch & 3;
      float b2 = 0.f;
      for (int q = g; q < 256; q += 8) b2 += ls2[q][r];
      ws[WS_BNP + bnb * 64 + t] = b2;
    }
  }
}

// ---- K2: fold (block 0, concurrent) + sparse aggregation (blocks 1..2048) ----
#define AGG_STEP(d) { \
    float vv = pv[d]; \
    v4f t0 = pb0[d], t1 = pb1[d]; \
    float2 p = shu.pl[row * 69 + k + 4 + d]; \
    int off = __float_as_int(p.x) + fo; \
    pv[d] = p.y; \
    pb0[d] = *(const v4f*)(xb0 + off); \
    pb1[d] = *(const v4f*)(xb1 + off); \
    acc0 += vv * t0; acc1 += vv * t1; }

__global__ void __launch_bounds__(256, 8)
k_agg(const float* __restrict__ x,
      const float* __restrict__ gamma, const float* __restrict__ beta,
      const float* __restrict__ Wg, const float* __restrict__ bg,
      const float* __restrict__ Wih, const float* __restrict__ bih,
      const float* __restrict__ Whh, const float* __restrict__ bhh,
      float* __restrict__ ws) {
  __shared__ union {
    float2 pl[32 * 69];                 // 17,664 B (agg)
    struct {                            // 15,488 B (fold)
      unsigned short wx16[32 * 192];
      float us[192], vs[192];
      float bns[64], scale[32], shift[32], ps[32];
      float bnp4[4][64];
    } fo;
  } shu;
  int tid = threadIdx.x;
  if (blockIdx.x == 0) {
    // ---- fold: BN reduce + compose fp16 A-fragments (hidden under agg blocks) ----
    {
      int g = tid >> 6, c = tid & 63;
      float a = 0.f;
      for (int i = 0; i < 64; i++) a += ws[WS_BNP + (size_t)(g + 4 * i) * 64 + c];
      shu.fo.bnp4[g][c] = a;
    }
    __syncthreads();
    if (tid < 64)
      shu.fo.bns[tid] = shu.fo.bnp4[0][tid] + shu.fo.bnp4[1][tid] + shu.fo.bnp4[2][tid] + shu.fo.bnp4[3][tid];
    __syncthreads();
    if (tid < 32) {
      float cntf = (float)(B_ * T_ * N_);
      float mean = shu.fo.bns[tid] / cntf;
      float var = shu.fo.bns[32 + tid] / cntf - mean * mean;
      float sc = gamma[tid] * rsqrtf(var + EPS_);
      shu.fo.scale[tid] = sc;
      shu.fo.shift[tid] = beta[tid] - mean * sc;
    }
    __syncthreads();
    if (tid < 32) {
      float acc = 0.f;
      for (int f = 0; f < 32; f++) acc += shu.fo.shift[f] * Wg[f * 32 + tid];
      shu.fo.ps[tid] = acc;
    }
    __syncthreads();
    for (int e = tid; e < 32 * 192; e += 256) {
      int f = e / 192, j = e % 192;
      float acc = 0.f;
#pragma unroll
      for (int c = 0; c < 32; c++) acc += Wg[f * 32 + c] * Wih[c * 192 + j];
      shu.fo.wx16[e] = f2h(shu.fo.scale[f] * acc);
    }
    if (tid < 192) {
      float au = 0.f, av = 0.f;
#pragma unroll
      for (int c = 0; c < 32; c++) { au += shu.fo.ps[c] * Wih[c * 192 + tid]; av += bg[c] * Wih[c * 192 + tid]; }
      shu.fo.us[tid] = au; shu.fo.vs[tid] = av + bih[tid];
    }
    __syncthreads();
    int w = tid >> 6, L = tid & 63, q = L >> 4, c = L & 15;
    uint32_t* wsu = (uint32_t*)ws;
    for (int fi = w; fi < 52; fi += 4) {
      int mt, kt;
      if (fi < 32)      { mt = fi >> 2;            kt = fi & 3; }
      else if (fi < 40) { mt = 8 + ((fi - 32) >> 1); kt = (fi & 1) ? 3 : 0; }
      else              { int r = fi - 40; mt = 12 + r / 3; kt = 1 + r % 3; }
      int cls = mt >> 2;
      int col = (cls < 2) ? mt * 16 + c : 128 + (mt & 3) * 16 + c;
#pragma unroll
      for (int d = 0; d < 4; d++) {
        float a01[2];
#pragma unroll
        for (int h2 = 0; h2 < 2; h2++) {
          int k = kt * 32 + q * 8 + 2 * d + h2;
          float v;
          if (k < 32)       v = (cls == 3) ? 0.f : h2f(shu.fo.wx16[k * 192 + col]);
          else if (k < 96)  v = (cls == 2) ? 0.f : Whh[(k - 32) * 192 + col];
          else if (k == 96) v = (cls == 3) ? 0.f : shu.fo.us[col];
          else if (k == 97) v = (cls < 2) ? (shu.fo.vs[col] + bhh[col]) : (cls == 2 ? shu.fo.vs[col] : bhh[col]);
          else              v = 0.f;
          a01[h2] = v;
        }
        wsu[WS_FRG + fi * 256 + L * 4 + d] = f16pair(a01[0], a01[1]);
      }
    }
    return;
  }
  // ---- aggregation: 32 rows x 8 f4-lanes, 2 bt streams, depth-4 pipeline ----
  int idx = blockIdx.x - 1;
  int chunk = idx & 15;                 // 16 chunks of 2 bt; idx%8 uniform per chunk -> XCD pin
  int mg = idx >> 4;                    // [0,128): 32-row group
  int row = tid >> 3, f4 = tid & 7;
  int m = mg * 32 + row;
  const int* deg = (const int*)&ws[WS_DEG];
  const float2* pair = (const float2*)&ws[WS_PAIR];
  for (int qq = tid; qq < 32 * 68; qq += 256) {
    int r = qq / 68, sl = qq - r * 68;
    shu.pl[r * 69 + sl] = pair[(size_t)(mg * 32 + r) * CAP_ + sl];
  }
  __syncthreads();
  int d0 = deg[m];
  int dm = min(d0, 64);
  int bound = dm;                       // wave-uniform max over the wave's 8 rows
  bound = max(bound, __shfl_xor(bound, 8, 64));
  bound = max(bound, __shfl_xor(bound, 16, 64));
  bound = max(bound, __shfl_xor(bound, 32, 64));
  bound = (bound + 3) & ~3;             // mult of 4; slots < 68 valid/zeroed
  int bt0 = chunk * 2;
  const float* xb0 = x + (size_t)bt0 * N_ * F_;
  const float* xb1 = xb0 + N_ * F_;
  int fo = f4 * 4;
  v4f acc0 = {0,0,0,0}, acc1 = {0,0,0,0};
  v4f pb0[4], pb1[4];
  float pv[4];
#pragma unroll
  for (int d = 0; d < 4; d++) {         // prologue: 8 loads in flight
    float2 p = shu.pl[row * 69 + d];
    int off = __float_as_int(p.x) + fo;
    pv[d] = p.y;
    pb0[d] = *(const v4f*)(xb0 + off);
    pb1[d] = *(const v4f*)(xb1 + off);
  }
  for (int k = 0; k < bound; k += 4) {
    AGG_STEP(0) AGG_STEP(1) AGG_STEP(2) AGG_STEP(3)
  }
  if (d0 > 64) {                        // statistically never (avg deg ~32)
    for (int k = 64; k < d0; k++) {
      float2 p = pair[(size_t)m * CAP_ + k];
      int off = __float_as_int(p.x) + fo;
      float vv = p.y;
      acc0 += vv * *(const v4f*)(xb0 + off);
      acc1 += vv * *(const v4f*)(xb1 + off);
    }
  }
  size_t ob = (size_t)bt0 * N_ * F_ + m * F_ + fo;
  *(v4f*)(ws + WS_XA + ob) = acc0;
  *(v4f*)(ws + WS_XA + ob + (size_t)N_ * F_) = acc1;
}

// ---- K3: MFMA GRU; frg block-copied from ws, xa software-pipelined from global ----
#define LDA(fi) (*(const half8*)(frg + (fi)*256 + L*4))
#define DO1(mt, fi, BH, BL) { half8 af = LDA(fi); \
  acc[mt] = __builtin_amdgcn_mfma_f32_16x16x32_f16(af, BH, acc[mt], 0, 0, 0); \
  acc[mt] = __builtin_amdgcn_mfma_f32_16x16x32_f16(af, BL, acc[mt], 0, 0, 0); }

__global__ void __launch_bounds__(256, 1)
k_gru(const float* __restrict__ Wd, const float* __restrict__ bd,
      const float* __restrict__ ws, float* __restrict__ out) {
  __shared__ uint32_t frg[52 * 256];     // 53 KB weight fragments
  __shared__ uint32_t hx[4 * 1344];      // per-wave h-exchange, stride 21
  {
    const uint4* gf = (const uint4*)(ws + WS_FRG);
    uint4* sf = (uint4*)frg;
    for (int i = threadIdx.x; i < 52 * 64; i += 256) sf[i] = gf[i];
  }
  __syncthreads();
  int wid = threadIdx.x >> 6, L = threadIdx.x & 63;
  int q = L >> 4, c = L & 15;
  uint32_t* hxw = hx + wid * 1344;
  int row0 = blockIdx.x * 64 + wid * 16;
  int b = row0 >> 12;
  int nb = row0 & (N_ - 1);
  float wdv[4][4];
#pragma unroll
  for (int g = 0; g < 4; g++)
#pragma unroll
    for (int r = 0; r < 4; r++) wdv[g][r] = Wd[16 * g + 4 * q + r];
  float bdv = bd[0];
  HU b3h, b3l;
#pragma unroll
  for (int d = 0; d < 4; d++) { b3h.u[d] = 0; b3l.u[d] = 0; }
  {
    float rsv = ws[WS_ROWSUM + nb + c];
    uint32_t rhi, rlo;
    sp2(rsv, 1.0f, rhi, rlo);
    if (q == 0) { b3h.u[0] = rhi; b3l.u[0] = rlo & 0xFFFFu; }
  }
  float h[4][4];
#pragma unroll
  for (int g = 0; g < 4; g++)
#pragma unroll
    for (int r = 0; r < 4; r++) h[g][r] = 0.f;

  const float* xab = ws + WS_XA;
  size_t xo0 = ((size_t)(b * T_) * N_ + nb + c) * F_ + q * 8;
  float4 xaA = *(const float4*)(xab + xo0);
  float4 xaB = *(const float4*)(xab + xo0 + 4);

  for (int t = 0; t < T_; t++) {
    float4 nxA, nxB;
    if (t < T_ - 1) {
      size_t xo = ((size_t)(b * T_ + t + 1) * N_ + nb + c) * F_ + q * 8;
      nxA = *(const float4*)(xab + xo);
      nxB = *(const float4*)(xab + xo + 4);
    }
#pragma unroll
    for (int g = 0; g < 4; g++)
#pragma unroll
      for (int rp = 0; rp < 2; rp++) {
        uint32_t phi, plo;
        sp2(h[g][2 * rp], h[g][2 * rp + 1], phi, plo);
        int pidx = 8 * g + 2 * q + rp;
        hxw[(pidx * 2 + 0) * 21 + c] = phi;
        hxw[(pidx * 2 + 1) * 21 + c] = plo;
      }
    HU b1h, b1l, b2h, b2l;
#pragma unroll
    for (int d = 0; d < 4; d++) {
      b1h.u[d] = hxw[((4 * q + d) * 2 + 0) * 21 + c];
      b1l.u[d] = hxw[((4 * q + d) * 2 + 1) * 21 + c];
      b2h.u[d] = hxw[((16 + 4 * q + d) * 2 + 0) * 21 + c];
      b2l.u[d] = hxw[((16 + 4 * q + d) * 2 + 1) * 21 + c];
    }
    v4f acc[16];
#pragma unroll
    for (int i = 0; i < 16; i++) acc[i] = (v4f){0.f, 0.f, 0.f, 0.f};
    DO1(0,1,b1h.v,b1l.v)  DO1(1,5,b1h.v,b1l.v)  DO1(2,9,b1h.v,b1l.v)  DO1(3,13,b1h.v,b1l.v)
    DO1(4,17,b1h.v,b1l.v) DO1(5,21,b1h.v,b1l.v) DO1(6,25,b1h.v,b1l.v) DO1(7,29,b1h.v,b1l.v)
    DO1(12,40,b1h.v,b1l.v) DO1(13,43,b1h.v,b1l.v) DO1(14,46,b1h.v,b1l.v) DO1(15,49,b1h.v,b1l.v)
    DO1(0,2,b2h.v,b2l.v)  DO1(1,6,b2h.v,b2l.v)  DO1(2,10,b2h.v,b2l.v) DO1(3,14,b2h.v,b2l.v)
    DO1(4,18,b2h.v,b2l.v) DO1(5,22,b2h.v,b2l.v) DO1(6,26,b2h.v,b2l.v) DO1(7,30,b2h.v,b2l.v)
    DO1(12,41,b2h.v,b2l.v) DO1(13,44,b2h.v,b2l.v) DO1(14,47,b2h.v,b2l.v) DO1(15,50,b2h.v,b2l.v)
    DO1(0,3,b3h.v,b3l.v)  DO1(1,7,b3h.v,b3l.v)  DO1(2,11,b3h.v,b3l.v) DO1(3,15,b3h.v,b3l.v)
    DO1(4,19,b3h.v,b3l.v) DO1(5,23,b3h.v,b3l.v) DO1(6,27,b3h.v,b3l.v) DO1(7,31,b3h.v,b3l.v)
    DO1(8,33,b3h.v,b3l.v) DO1(9,35,b3h.v,b3l.v) DO1(10,37,b3h.v,b3l.v) DO1(11,39,b3h.v,b3l.v)
    DO1(12,42,b3h.v,b3l.v) DO1(13,45,b3h.v,b3l.v) DO1(14,48,b3h.v,b3l.v) DO1(15,51,b3h.v,b3l.v)
    HU b0h, b0l;
    sp2(xaA.x, xaA.y, b0h.u[0], b0l.u[0]);
    sp2(xaA.z, xaA.w, b0h.u[1], b0l.u[1]);
    sp2(xaB.x, xaB.y, b0h.u[2], b0l.u[2]);
    sp2(xaB.z, xaB.w, b0h.u[3], b0l.u[3]);
    DO1(0,0,b0h.v,b0l.v)  DO1(1,4,b0h.v,b0l.v)  DO1(2,8,b0h.v,b0l.v)  DO1(3,12,b0h.v,b0l.v)
    DO1(4,16,b0h.v,b0l.v) DO1(5,20,b0h.v,b0l.v) DO1(6,24,b0h.v,b0l.v) DO1(7,28,b0h.v,b0l.v)
    DO1(8,32,b0h.v,b0l.v) DO1(9,34,b0h.v,b0l.v) DO1(10,36,b0h.v,b0l.v) DO1(11,38,b0h.v,b0l.v)
    float o = 0.f;
#pragma unroll
    for (int g = 0; g < 4; g++)
#pragma unroll
      for (int r = 0; r < 4; r++) {
        float rr = sigm_f(acc[g][r]);
        float z  = sigm_f(acc[4 + g][r]);
        float nn = 2.0f * sigm_f(2.0f * (acc[8 + g][r] + rr * acc[12 + g][r])) - 1.0f;
        float hn = z * (h[g][r] - nn) + nn;
        h[g][r] = hn;
        o += wdv[g][r] * hn;
      }
    o += __shfl_xor(o, 16, 64);
    o += __shfl_xor(o, 32, 64);
    if (L < 16) out[(size_t)(b * T_ + t) * N_ + nb + L] = o + bdv;
    xaA = nxA; xaB = nxB;
  }
}

extern "C" void kernel_launch(void* const* d_in, const int* in_sizes, int n_in,
                              void* d_out, int out_size, void* d_ws, size_t ws_size,
                              hipStream_t stream) {
  const float* x     = (const float*)d_in[0];
  const float* adj   = (const float*)d_in[1];
  const float* gamma = (const float*)d_in[2];
  const float* beta  = (const float*)d_in[3];
  const float* Wg    = (const float*)d_in[4];
  const float* bg    = (const float*)d_in[5];
  const float* Wih   = (const float*)d_in[6];
  const float* Whh   = (const float*)d_in[7];
  const float* bih   = (const float*)d_in[8];
  const float* bhh   = (const float*)d_in[9];
  const float* Wd    = (const float*)d_in[10];
  const float* bd    = (const float*)d_in[11];
  float* ws = (float*)d_ws;
  float* out = (float*)d_out;

  k_pre<<<2048 + 256, 256, 0, stream>>>(x, adj, ws);
  k_agg<<<2048 + 1, 256, 0, stream>>>(x, gamma, beta, Wg, bg, Wih, bih, Whh, bhh, ws);
  k_gru<<<256, 256, 0, stream>>>(Wd, bd, ws, out);
}

// Round 14
// 206.451 us; speedup vs baseline: 1.1765x; 1.1765x over previous
//
#include <hip/hip_runtime.h>
#include <hip/hip_bf16.h>
#include <stdint.h>

#define B_ 4
#define T_ 8
#define N_ 4096
#define F_ 32
#define BT_ (B_*T_)
#define ROWS_ (B_*N_)
#define CAP_ 128
#define EPS_ 1e-5f
#define NELEM_ (B_*T_*N_*F_)

// ---- workspace layout (float offsets) ----
#define WS_BNS    0                       // 64 floats, atomic-accumulated BN sums
#define WS_ROWSUM 16384                   // 4096
#define WS_DEG    (WS_ROWSUM + 4096)      // 4096 (int)
#define WS_FRG    (WS_DEG + 4096)         // 52 frags * 64 lanes * 4 dwords
#define WS_PAIR   (WS_FRG + 52*256)       // 4096*CAP_*2  (idx*F_ as float-bits, val)
#define WS_XA     (WS_PAIR + 4096*CAP_*2) // BT_*N_*F_

typedef float v4f __attribute__((ext_vector_type(4)));
typedef _Float16 half8 __attribute__((ext_vector_type(8)));
union HU { uint32_t u[4]; half8 v; };

__device__ inline float sigm_f(float x) {
  return __builtin_amdgcn_rcpf(1.0f + __expf(-x));
}
__device__ inline uint32_t f16pair(float a, float b) {
  union { _Float16 h; unsigned short s; } x, y;
  x.h = (_Float16)a; y.h = (_Float16)b;
  return (uint32_t)x.s | ((uint32_t)y.s << 16);
}
__device__ inline void sp2(float a0, float a1, uint32_t& hi, uint32_t& lo) {
  _Float16 h0 = (_Float16)a0, h1 = (_Float16)a1;
  float r0 = a0 - (float)h0, r1 = a1 - (float)h1;
  union { _Float16 h; unsigned short s; } u0, u1, v0, v1;
  u0.h = h0; u1.h = h1; v0.h = (_Float16)r0; v1.h = (_Float16)r1;
  hi = (uint32_t)u0.s | ((uint32_t)u1.s << 16);
  lo = (uint32_t)v0.s | ((uint32_t)v1.s << 16);
}

// ---- K1: merged CSR build (blocks 0..4095) + BN partial stats (4096..4351) ----
__global__ void __launch_bounds__(256)
k_pre(const float* __restrict__ x, const float* __restrict__ A, float* __restrict__ ws) {
  if (blockIdx.x < 4096) {
    int m = blockIdx.x;
    __shared__ int cnt;
    __shared__ float wsum[4];
    if (threadIdx.x == 0) cnt = 0;
    __syncthreads();
    int* deg = (int*)&ws[WS_DEG];
    float2* pair = (float2*)&ws[WS_PAIR];
    const float4* A4 = (const float4*)(A + (size_t)m * N_);
    float4 av4[4];
#pragma unroll
    for (int i = 0; i < 4; i++) av4[i] = A4[threadIdx.x + 256 * i];   // 4 loads in flight
    float lsum = 0.f;
#pragma unroll
    for (int i = 0; i < 4; i++) {
      float av[4] = {av4[i].x, av4[i].y, av4[i].z, av4[i].w};
      int nb4 = (threadIdx.x + 256 * i) * 4;
#pragma unroll
      for (int r = 0; r < 4; r++) {
        float a = av[r];
        if (a != 0.0f) {
          int p = atomicAdd(&cnt, 1);
          if (p < CAP_) pair[(size_t)m * CAP_ + p] = make_float2(__int_as_float((nb4 + r) * F_), a);
          lsum += a;
        }
      }
    }
#pragma unroll
    for (int off = 32; off > 0; off >>= 1) lsum += __shfl_xor(lsum, off, 64);  // wave reduce
    if ((threadIdx.x & 63) == 0) wsum[threadIdx.x >> 6] = lsum;
    __syncthreads();                     // cnt + wsum final
    int c = cnt;
    for (int p = c + threadIdx.x; p < 68; p += 256)   // zero-fill incl. prefetch pad
      pair[(size_t)m * CAP_ + p] = make_float2(__int_as_float(0), 0.0f);
    if (threadIdx.x == 0) {
      deg[m] = min(c, CAP_);
      ws[WS_ROWSUM + m] = wsum[0] + wsum[1] + wsum[2] + wsum[3];
    }
  } else {
    int bnb = blockIdx.x - 4096;
    const float4* x4 = (const float4*)x;
    int tid = bnb * 256 + threadIdx.x;
    float s[4] = {0,0,0,0}, s2[4] = {0,0,0,0};
    for (int i = tid; i < NELEM_ / 4; i += 256 * 256) {
      float4 v = x4[i];
      s[0] += v.x; s2[0] += v.x * v.x;
      s[1] += v.y; s2[1] += v.y * v.y;
      s[2] += v.z; s2[2] += v.z * v.z;
      s[3] += v.w; s2[3] += v.w * v.w;
    }
    __shared__ float ls[256][4], ls2[256][4];
#pragma unroll
    for (int r = 0; r < 4; r++) { ls[threadIdx.x][r] = s[r]; ls2[threadIdx.x][r] = s2[r]; }
    __syncthreads();
    int t = threadIdx.x;
    if (t < 32) {                       // channel c = 4*(q&7)+r
      int g = t >> 2, r = t & 3;
      float a = 0.f;
      for (int q = g; q < 256; q += 8) a += ls[q][r];
      atomicAdd(&ws[WS_BNS + t], a);
    } else if (t < 64) {
      int cch = t - 32;
      int g = cch >> 2, r = cch & 3;
      float b2 = 0.f;
      for (int q = g; q < 256; q += 8) b2 += ls2[q][r];
      atomicAdd(&ws[WS_BNS + t], b2);
    }
  }
}

// ---- K2: one-block fold, LDS-staged (one parallel load burst, then LDS-only) ----
__global__ void __launch_bounds__(256)
k_fold(const float* __restrict__ gamma, const float* __restrict__ beta,
       const float* __restrict__ Wg, const float* __restrict__ bg,
       const float* __restrict__ Wih, const float* __restrict__ bih,
       const float* __restrict__ Whh, const float* __restrict__ bhh,
       float* __restrict__ ws) {
  __shared__ float fb[26144];            // 104 KB
  float* Wx_s  = fb;                     // 6144
  float* Wih_s = fb + 6144;              // 6144
  float* Whh_s = fb + 12288;             // 12288
  float* Wg_s  = fb + 24576;             // 1024
  float* Us_s  = fb + 25600;             // 192
  float* Vs_s  = fb + 25792;             // 192
  float* bns   = fb + 25984;             // 64
  float* scale_s = fb + 26048;           // 32
  float* shift_s = fb + 26080;           // 32
  float* p_s   = fb + 26112;             // 32
  int tid = threadIdx.x;
#pragma unroll
  for (int i = tid; i < 1536; i += 256) ((float4*)Wih_s)[i] = ((const float4*)Wih)[i];
#pragma unroll
  for (int i = tid; i < 3072; i += 256) ((float4*)Whh_s)[i] = ((const float4*)Whh)[i];
  if (tid < 256) { ((float4*)Wg_s)[tid] = ((const float4*)Wg)[tid]; }
  if (tid < 64) bns[tid] = ws[WS_BNS + tid];
  __syncthreads();
  if (tid < 32) {
    float cntf = (float)(B_ * T_ * N_);
    float mean = bns[tid] / cntf;
    float var = bns[32 + tid] / cntf - mean * mean;
    float sc = gamma[tid] * rsqrtf(var + EPS_);
    scale_s[tid] = sc;
    shift_s[tid] = beta[tid] - mean * sc;
  }
  __syncthreads();
  if (tid < 32) {
    float acc = 0.f;
    for (int f = 0; f < 32; f++) acc += shift_s[f] * Wg_s[f * 32 + tid];
    p_s[tid] = acc;
  }
  __syncthreads();
  for (int e = tid; e < 32 * 192; e += 256) {
    int f = e / 192, j = e % 192;
    float acc = 0.f;
#pragma unroll
    for (int c = 0; c < 32; c++) acc += Wg_s[f * 32 + c] * Wih_s[c * 192 + j];
    Wx_s[e] = scale_s[f] * acc;
  }
  if (tid < 192) {
    float au = 0.f, av = 0.f;
#pragma unroll
    for (int c = 0; c < 32; c++) { au += p_s[c] * Wih_s[c * 192 + tid]; av += bg[c] * Wih_s[c * 192 + tid]; }
    Us_s[tid] = au; Vs_s[tid] = av + bih[tid];
  }
  __syncthreads();
  int w = tid >> 6, L = tid & 63, q = L >> 4, c = L & 15;
  uint32_t* wsu = (uint32_t*)ws;
  for (int fi = w; fi < 52; fi += 4) {
    int mt, kt;
    if (fi < 32)      { mt = fi >> 2;            kt = fi & 3; }
    else if (fi < 40) { mt = 8 + ((fi - 32) >> 1); kt = (fi & 1) ? 3 : 0; }
    else              { int r = fi - 40; mt = 12 + r / 3; kt = 1 + r % 3; }
    int cls = mt >> 2;
    int col = (cls < 2) ? mt * 16 + c : 128 + (mt & 3) * 16 + c;
#pragma unroll
    for (int d = 0; d < 4; d++) {
      float a01[2];
#pragma unroll
      for (int h2 = 0; h2 < 2; h2++) {
        int k = kt * 32 + q * 8 + 2 * d + h2;
        float v;
        if (k < 32)       v = (cls == 3) ? 0.f : Wx_s[k * 192 + col];
        else if (k < 96)  v = (cls == 2) ? 0.f : Whh_s[(k - 32) * 192 + col];
        else if (k == 96) v = (cls == 3) ? 0.f : Us_s[col];
        else if (k == 97) v = (cls < 2) ? (Vs_s[col] + bhh[col]) : (cls == 2 ? Vs_s[col] : bhh[col]);
        else              v = 0.f;
        a01[h2] = v;
      }
      wsu[WS_FRG + fi * 256 + L * 4 + d] = f16pair(a01[0], a01[1]);
    }
  }
}

// ---- K3: sparse aggregation, 2 bt streams, depth-4 pipeline, 8 blocks/CU ----
#define AGG_STEP(d) { \
    float vv = pv[d]; \
    v4f t0 = pb0[d], t1 = pb1[d]; \
    float2 p = pl[row * 69 + k + 4 + d]; \
    int off = __float_as_int(p.x) + fo; \
    pv[d] = p.y; \
    pb0[d] = *(const v4f*)(xb0 + off); \
    pb1[d] = *(const v4f*)(xb1 + off); \
    acc0 += vv * t0; acc1 += vv * t1; }

__global__ void __launch_bounds__(256, 8)
k_agg(const float* __restrict__ x, float* __restrict__ ws) {
  __shared__ float2 pl[32 * 69];        // 17.7 KB
  int tid = threadIdx.x;
  int chunk = blockIdx.x & 15;          // 16 chunks of 2 bt; XCD = blockIdx%8 pins slices
  int mg = blockIdx.x >> 4;             // [0,128): 32-row group
  int row = tid >> 3, f4 = tid & 7;
  int m = mg * 32 + row;
  const int* deg = (const int*)&ws[WS_DEG];
  const float2* pair = (const float2*)&ws[WS_PAIR];
  for (int qq = tid; qq < 32 * 68; qq += 256) {
    int r = qq / 68, sl = qq - r * 68;
    pl[r * 69 + sl] = pair[(size_t)(mg * 32 + r) * CAP_ + sl];
  }
  __syncthreads();
  int d0 = deg[m];
  int dm = min(d0, 64);
  int bound = dm;                       // wave-uniform max over the wave's 8 rows
  bound = max(bound, __shfl_xor(bound, 8, 64));
  bound = max(bound, __shfl_xor(bound, 16, 64));
  bound = max(bound, __shfl_xor(bound, 32, 64));
  bound = (bound + 3) & ~3;             // mult of 4; slots < 68 valid/zeroed
  int bt0 = chunk * 2;
  const float* xb0 = x + (size_t)bt0 * N_ * F_;
  const float* xb1 = xb0 + N_ * F_;
  int fo = f4 * 4;
  v4f acc0 = {0,0,0,0}, acc1 = {0,0,0,0};
  v4f pb0[4], pb1[4];
  float pv[4];
#pragma unroll
  for (int d = 0; d < 4; d++) {         // prologue: 8 loads in flight
    float2 p = pl[row * 69 + d];
    int off = __float_as_int(p.x) + fo;
    pv[d] = p.y;
    pb0[d] = *(const v4f*)(xb0 + off);
    pb1[d] = *(const v4f*)(xb1 + off);
  }
  for (int k = 0; k < bound; k += 4) {
    AGG_STEP(0) AGG_STEP(1) AGG_STEP(2) AGG_STEP(3)
  }
  if (d0 > 64) {                        // statistically never (avg deg ~32)
    for (int k = 64; k < d0; k++) {
      float2 p = pair[(size_t)m * CAP_ + k];
      int off = __float_as_int(p.x) + fo;
      float vv = p.y;
      acc0 += vv * *(const v4f*)(xb0 + off);
      acc1 += vv * *(const v4f*)(xb1 + off);
    }
  }
  size_t ob = (size_t)bt0 * N_ * F_ + m * F_ + fo;
  *(v4f*)(ws + WS_XA + ob) = acc0;
  *(v4f*)(ws + WS_XA + ob + (size_t)N_ * F_) = acc1;
}

// ---- K4: MFMA GRU; frg block-copied from ws ----
#define LDA(fi) (*(const half8*)(frg + (fi)*256 + L*4))
#define DO1(mt, fi, BH, BL) { half8 af = LDA(fi); \
  acc[mt] = __builtin_amdgcn_mfma_f32_16x16x32_f16(af, BH, acc[mt], 0, 0, 0); \
  acc[mt] = __builtin_amdgcn_mfma_f32_16x16x32_f16(af, BL, acc[mt], 0, 0, 0); }

__global__ void __launch_bounds__(256, 1)
k_gru(const float* __restrict__ Wd, const float* __restrict__ bd,
      const float* __restrict__ ws, float* __restrict__ out) {
  __shared__ uint32_t frg[52 * 256];     // 53 KB weight fragments
  __shared__ uint32_t hx[4 * 1344];      // per-wave h-exchange, stride 21
  {
    const uint4* gf = (const uint4*)(ws + WS_FRG);
    uint4* sf = (uint4*)frg;
    for (int i = threadIdx.x; i < 52 * 64; i += 256) sf[i] = gf[i];
  }
  __syncthreads();
  int wid = threadIdx.x >> 6, L = threadIdx.x & 63;
  int q = L >> 4, c = L & 15;
  uint32_t* hxw = hx + wid * 1344;
  int row0 = blockIdx.x * 64 + wid * 16;
  int b = row0 >> 12;
  int nb = row0 & (N_ - 1);
  float wdv[4][4];
#pragma unroll
  for (int g = 0; g < 4; g++)
#pragma unroll
    for (int r = 0; r < 4; r++) wdv[g][r] = Wd[16 * g + 4 * q + r];
  float bdv = bd[0];
  HU b3h, b3l;
#pragma unroll
  for (int d = 0; d < 4; d++) { b3h.u[d] = 0; b3l.u[d] = 0; }
  {
    float rsv = ws[WS_ROWSUM + nb + c];
    uint32_t rhi, rlo;
    sp2(rsv, 1.0f, rhi, rlo);
    if (q == 0) { b3h.u[0] = rhi; b3l.u[0] = rlo & 0xFFFFu; }
  }
  float h[4][4];
#pragma unroll
  for (int g = 0; g < 4; g++)
#pragma unroll
    for (int r = 0; r < 4; r++) h[g][r] = 0.f;

  const float* xab = ws + WS_XA;
  size_t xo0 = ((size_t)(b * T_) * N_ + nb + c) * F_ + q * 8;
  float4 xaA = *(const float4*)(xab + xo0);
  float4 xaB = *(const float4*)(xab + xo0 + 4);

  for (int t = 0; t < T_; t++) {
    float4 nxA, nxB;
    if (t < T_ - 1) {
      size_t xo = ((size_t)(b * T_ + t + 1) * N_ + nb + c) * F_ + q * 8;
      nxA = *(const float4*)(xab + xo);
      nxB = *(const float4*)(xab + xo + 4);
    }
#pragma unroll
    for (int g = 0; g < 4; g++)
#pragma unroll
      for (int rp = 0; rp < 2; rp++) {
        uint32_t phi, plo;
        sp2(h[g][2 * rp], h[g][2 * rp + 1], phi, plo);
        int pidx = 8 * g + 2 * q + rp;
        hxw[(pidx * 2 + 0) * 21 + c] = phi;
        hxw[(pidx * 2 + 1) * 21 + c] = plo;
      }
    HU b1h, b1l, b2h, b2l;
#pragma unroll
    for (int d = 0; d < 4; d++) {
      b1h.u[d] = hxw[((4 * q + d) * 2 + 0) * 21 + c];
      b1l.u[d] = hxw[((4 * q + d) * 2 + 1) * 21 + c];
      b2h.u[d] = hxw[((16 + 4 * q + d) * 2 + 0) * 21 + c];
      b2l.u[d] = hxw[((16 + 4 * q + d) * 2 + 1) * 21 + c];
    }
    v4f acc[16];
#pragma unroll
    for (int i = 0; i < 16; i++) acc[i] = (v4f){0.f, 0.f, 0.f, 0.f};
    DO1(0,1,b1h.v,b1l.v)  DO1(1,5,b1h.v,b1l.v)  DO1(2,9,b1h.v,b1l.v)  DO1(3,13,b1h.v,b1l.v)
    DO1(4,17,b1h.v,b1l.v) DO1(5,21,b1h.v,b1l.v) DO1(6,25,b1h.v,b1l.v) DO1(7,29,b1h.v,b1l.v)
    DO1(12,40,b1h.v,b1l.v) DO1(13,43,b1h.v,b1l.v) DO1(14,46,b1h.v,b1l.v) DO1(15,49,b1h.v,b1l.v)
    DO1(0,2,b2h.v,b2l.v)  DO1(1,6,b2h.v,b2l.v)  DO1(2,10,b2h.v,b2l.v) DO1(3,14,b2h.v,b2l.v)
    DO1(4,18,b2h.v,b2l.v) DO1(5,22,b2h.v,b2l.v) DO1(6,26,b2h.v,b2l.v) DO1(7,30,b2h.v,b2l.v)
    DO1(12,41,b2h.v,b2l.v) DO1(13,44,b2h.v,b2l.v) DO1(14,47,b2h.v,b2l.v) DO1(15,50,b2h.v,b2l.v)
    DO1(0,3,b3h.v,b3l.v)  DO1(1,7,b3h.v,b3l.v)  DO1(2,11,b3h.v,b3l.v) DO1(3,15,b3h.v,b3l.v)
    DO1(4,19,b3h.v,b3l.v) DO1(5,23,b3h.v,b3l.v) DO1(6,27,b3h.v,b3l.v) DO1(7,31,b3h.v,b3l.v)
    DO1(8,33,b3h.v,b3l.v) DO1(9,35,b3h.v,b3l.v) DO1(10,37,b3h.v,b3l.v) DO1(11,39,b3h.v,b3l.v)
    DO1(12,42,b3h.v,b3l.v) DO1(13,45,b3h.v,b3l.v) DO1(14,48,b3h.v,b3l.v) DO1(15,51,b3h.v,b3l.v)
    HU b0h, b0l;
    sp2(xaA.x, xaA.y, b0h.u[0], b0l.u[0]);
    sp2(xaA.z, xaA.w, b0h.u[1], b0l.u[1]);
    sp2(xaB.x, xaB.y, b0h.u[2], b0l.u[2]);
    sp2(xaB.z, xaB.w, b0h.u[3], b0l.u[3]);
    DO1(0,0,b0h.v,b0l.v)  DO1(1,4,b0h.v,b0l.v)  DO1(2,8,b0h.v,b0l.v)  DO1(3,12,b0h.v,b0l.v)
    DO1(4,16,b0h.v,b0l.v) DO1(5,20,b0h.v,b0l.v) DO1(6,24,b0h.v,b0l.v) DO1(7,28,b0h.v,b0l.v)
    DO1(8,32,b0h.v,b0l.v) DO1(9,34,b0h.v,b0l.v) DO1(10,36,b0h.v,b0l.v) DO1(11,38,b0h.v,b0l.v)
    float o = 0.f;
#pragma unroll
    for (int g = 0; g < 4; g++)
#pragma unroll
      for (int r = 0; r < 4; r++) {
        float rr = sigm_f(acc[g][r]);
        float z  = sigm_f(acc[4 + g][r]);
        float nn = 2.0f * sigm_f(2.0f * (acc[8 + g][r] + rr * acc[12 + g][r])) - 1.0f;
        float hn = z * (h[g][r] - nn) + nn;
        h[g][r] = hn;
        o += wdv[g][r] * hn;
      }
    o += __shfl_xor(o, 16, 64);
    o += __shfl_xor(o, 32, 64);
    if (L < 16) out[(size_t)(b * T_ + t) * N_ + nb + L] = o + bdv;
    xaA = nxA; xaB = nxB;
  }
}

extern "C" void kernel_launch(void* const* d_in, const int* in_sizes, int n_in,
                              void* d_out, int out_size, void* d_ws, size_t ws_size,
                              hipStream_t stream) {
  const float* x     = (const float*)d_in[0];
  const float* adj   = (const float*)d_in[1];
  const float* gamma = (const float*)d_in[2];
  const float* beta  = (const float*)d_in[3];
  const float* Wg    = (const float*)d_in[4];
  const float* bg    = (const float*)d_in[5];
  const float* Wih   = (const float*)d_in[6];
  const float* Whh   = (const float*)d_in[7];
  const float* bih   = (const float*)d_in[8];
  const float* bhh   = (const float*)d_in[9];
  const float* Wd    = (const float*)d_in[10];
  const float* bd    = (const float*)d_in[11];
  float* ws = (float*)d_ws;
  float* out = (float*)d_out;

  hipMemsetAsync(ws + WS_BNS, 0, 64 * sizeof(float), stream);   // zero BN accumulators
  k_pre<<<4096 + 256, 256, 0, stream>>>(x, adj, ws);
  k_fold<<<1, 256, 0, stream>>>(gamma, beta, Wg, bg, Wih, bih, Whh, bhh, ws);
  k_agg<<<2048, 256, 0, stream>>>(x, ws);
  k_gru<<<256, 256, 0, stream>>>(Wd, bd, ws, out);
}

// Round 15
// 202.885 us; speedup vs baseline: 1.1972x; 1.0176x over previous
//
#include <hip/hip_runtime.h>
#include <hip/hip_bf16.h>
#include <stdint.h>

#define B_ 4
#define T_ 8
#define N_ 4096
#define F_ 32
#define BT_ (B_*T_)
#define ROWS_ (B_*N_)
#define CAP_ 128
#define EPS_ 1e-5f
#define NELEM_ (B_*T_*N_*F_)

// ---- workspace layout (float offsets) ----
#define WS_BNP    0                       // 256 * 64 per-block BN partials
#define WS_ROWSUM 16384                   // 4096
#define WS_DEG    (WS_ROWSUM + 4096)      // 4096 (int)
#define WS_FRG    (WS_DEG + 4096)         // 52 frags * 64 lanes * 4 dwords
#define WS_PAIR   (WS_FRG + 52*256)       // 4096*CAP_*2  (idx*F_ as float-bits, val)
#define WS_XA     (WS_PAIR + 4096*CAP_*2) // BT_*N_*F_

typedef float v4f __attribute__((ext_vector_type(4)));
typedef _Float16 half8 __attribute__((ext_vector_type(8)));
union HU { uint32_t u[4]; half8 v; };

__device__ inline float sigm_f(float x) {
  return __builtin_amdgcn_rcpf(1.0f + __expf(-x));
}
__device__ inline uint32_t f16pair(float a, float b) {
  union { _Float16 h; unsigned short s; } x, y;
  x.h = (_Float16)a; y.h = (_Float16)b;
  return (uint32_t)x.s | ((uint32_t)y.s << 16);
}
__device__ inline void sp2(float a0, float a1, uint32_t& hi, uint32_t& lo) {
  _Float16 h0 = (_Float16)a0, h1 = (_Float16)a1;
  float r0 = a0 - (float)h0, r1 = a1 - (float)h1;
  union { _Float16 h; unsigned short s; } u0, u1, v0, v1;
  u0.h = h0; u1.h = h1; v0.h = (_Float16)r0; v1.h = (_Float16)r1;
  hi = (uint32_t)u0.s | ((uint32_t)u1.s << 16);
  lo = (uint32_t)v0.s | ((uint32_t)v1.s << 16);
}

// ---- K1: CSR build, 2 rows/block (blocks 0..2047) + BN partials (2048..2303) ----
__global__ void __launch_bounds__(256)
k_pre(const float* __restrict__ x, const float* __restrict__ A, float* __restrict__ ws) {
  if (blockIdx.x < 2048) {
    int m0 = blockIdx.x * 2;
    __shared__ int cnt[2];
    __shared__ float wsum[4][2];
    if (threadIdx.x < 2) cnt[threadIdx.x] = 0;
    __syncthreads();
    int* deg = (int*)&ws[WS_DEG];
    float2* pair = (float2*)&ws[WS_PAIR];
    const float4* A4 = (const float4*)(A + (size_t)m0 * N_);
    float4 av4[8];
#pragma unroll
    for (int r = 0; r < 2; r++)
#pragma unroll
      for (int i = 0; i < 4; i++) av4[r * 4 + i] = A4[r * 1024 + threadIdx.x + 256 * i];  // 8 in flight
    float lsum[2] = {0.f, 0.f};
#pragma unroll
    for (int r = 0; r < 2; r++)
#pragma unroll
      for (int i = 0; i < 4; i++) {
        float av[4] = {av4[r*4+i].x, av4[r*4+i].y, av4[r*4+i].z, av4[r*4+i].w};
        int nb4 = (threadIdx.x + 256 * i) * 4;
#pragma unroll
        for (int e = 0; e < 4; e++) {
          float a = av[e];
          if (a != 0.0f) {
            int p = atomicAdd(&cnt[r], 1);
            if (p < CAP_) pair[(size_t)(m0 + r) * CAP_ + p] = make_float2(__int_as_float((nb4 + e) * F_), a);
            lsum[r] += a;
          }
        }
      }
#pragma unroll
    for (int r = 0; r < 2; r++) {
      float s = lsum[r];
#pragma unroll
      for (int off = 32; off > 0; off >>= 1) s += __shfl_xor(s, off, 64);
      if ((threadIdx.x & 63) == 0) wsum[threadIdx.x >> 6][r] = s;
    }
    __syncthreads();                     // cnt + wsum final
#pragma unroll
    for (int r = 0; r < 2; r++) {
      int c = cnt[r];
      for (int p = c + threadIdx.x; p < 68; p += 256)   // zero-fill incl. prefetch pad
        pair[(size_t)(m0 + r) * CAP_ + p] = make_float2(__int_as_float(0), 0.0f);
    }
    if (threadIdx.x < 2) {
      int r = threadIdx.x;
      deg[m0 + r] = min(cnt[r], CAP_);
      ws[WS_ROWSUM + m0 + r] = wsum[0][r] + wsum[1][r] + wsum[2][r] + wsum[3][r];
    }
  } else {
    int bnb = blockIdx.x - 2048;
    const float4* x4 = (const float4*)x;
    int tid = bnb * 256 + threadIdx.x;
    float s[4] = {0,0,0,0}, s2[4] = {0,0,0,0};
    for (int i = tid; i < NELEM_ / 4; i += 256 * 256) {
      float4 v = x4[i];
      s[0] += v.x; s2[0] += v.x * v.x;
      s[1] += v.y; s2[1] += v.y * v.y;
      s[2] += v.z; s2[2] += v.z * v.z;
      s[3] += v.w; s2[3] += v.w * v.w;
    }
    __shared__ float ls[256][4], ls2[256][4];
#pragma unroll
    for (int r = 0; r < 4; r++) { ls[threadIdx.x][r] = s[r]; ls2[threadIdx.x][r] = s2[r]; }
    __syncthreads();
    int t = threadIdx.x;
    if (t < 32) {                       // channel c = 4*(q&7)+r
      int g = t >> 2, r = t & 3;
      float a = 0.f;
      for (int q = g; q < 256; q += 8) a += ls[q][r];
      ws[WS_BNP + bnb * 64 + t] = a;
    } else if (t < 64) {
      int cch = t - 32;
      int g = cch >> 2, r = cch & 3;
      float b2 = 0.f;
      for (int q = g; q < 256; q += 8) b2 += ls2[q][r];
      ws[WS_BNP + bnb * 64 + t] = b2;
    }
  }
}

// ---- K2: one-block fold, LDS-staged; coalesced BNP reduce ----
__global__ void __launch_bounds__(256)
k_fold(const float* __restrict__ gamma, const float* __restrict__ beta,
       const float* __restrict__ Wg, const float* __restrict__ bg,
       const float* __restrict__ Wih, const float* __restrict__ bih,
       const float* __restrict__ Whh, const float* __restrict__ bhh,
       float* __restrict__ ws) {
  __shared__ float fb[26144];            // 104 KB
  __shared__ float bnp4[4][64];
  float* Wx_s  = fb;                     // 6144
  float* Wih_s = fb + 6144;              // 6144
  float* Whh_s = fb + 12288;             // 12288
  float* Wg_s  = fb + 24576;             // 1024
  float* Us_s  = fb + 25600;             // 192
  float* Vs_s  = fb + 25792;             // 192
  float* bns   = fb + 25984;             // 64
  float* scale_s = fb + 26048;           // 32
  float* shift_s = fb + 26080;           // 32
  float* p_s   = fb + 26112;             // 32
  int tid = threadIdx.x;
  // ---- staging burst + coalesced partial reduce ----
#pragma unroll
  for (int i = tid; i < 1536; i += 256) ((float4*)Wih_s)[i] = ((const float4*)Wih)[i];
#pragma unroll
  for (int i = tid; i < 3072; i += 256) ((float4*)Whh_s)[i] = ((const float4*)Whh)[i];
  if (tid < 256) { ((float4*)Wg_s)[tid] = ((const float4*)Wg)[tid]; }
  {                                      // bnp[256][64] -> bnp4[4][64], coalesced
    int g = tid >> 6, c = tid & 63;
    float a = 0.f;
    for (int i = 0; i < 64; i++) a += ws[WS_BNP + (size_t)(g + 4 * i) * 64 + c];
    bnp4[g][c] = a;
  }
  __syncthreads();
  if (tid < 64) bns[tid] = bnp4[0][tid] + bnp4[1][tid] + bnp4[2][tid] + bnp4[3][tid];
  __syncthreads();
  if (tid < 32) {
    float cntf = (float)(B_ * T_ * N_);
    float mean = bns[tid] / cntf;
    float var = bns[32 + tid] / cntf - mean * mean;
    float sc = gamma[tid] * rsqrtf(var + EPS_);
    scale_s[tid] = sc;
    shift_s[tid] = beta[tid] - mean * sc;
  }
  __syncthreads();
  if (tid < 32) {
    float acc = 0.f;
    for (int f = 0; f < 32; f++) acc += shift_s[f] * Wg_s[f * 32 + tid];
    p_s[tid] = acc;
  }
  __syncthreads();
  for (int e = tid; e < 32 * 192; e += 256) {
    int f = e / 192, j = e % 192;
    float acc = 0.f;
#pragma unroll
    for (int c = 0; c < 32; c++) acc += Wg_s[f * 32 + c] * Wih_s[c * 192 + j];
    Wx_s[e] = scale_s[f] * acc;
  }
  if (tid < 192) {
    float au = 0.f, av = 0.f;
#pragma unroll
    for (int c = 0; c < 32; c++) { au += p_s[c] * Wih_s[c * 192 + tid]; av += bg[c] * Wih_s[c * 192 + tid]; }
    Us_s[tid] = au; Vs_s[tid] = av + bih[tid];
  }
  __syncthreads();
  int w = tid >> 6, L = tid & 63, q = L >> 4, c = L & 15;
  uint32_t* wsu = (uint32_t*)ws;
  for (int fi = w; fi < 52; fi += 4) {
    int mt, kt;
    if (fi < 32)      { mt = fi >> 2;            kt = fi & 3; }
    else if (fi < 40) { mt = 8 + ((fi - 32) >> 1); kt = (fi & 1) ? 3 : 0; }
    else              { int r = fi - 40; mt = 12 + r / 3; kt = 1 + r % 3; }
    int cls = mt >> 2;
    int col = (cls < 2) ? mt * 16 + c : 128 + (mt & 3) * 16 + c;
#pragma unroll
    for (int d = 0; d < 4; d++) {
      float a01[2];
#pragma unroll
      for (int h2 = 0; h2 < 2; h2++) {
        int k = kt * 32 + q * 8 + 2 * d + h2;
        float v;
        if (k < 32)       v = (cls == 3) ? 0.f : Wx_s[k * 192 + col];
        else if (k < 96)  v = (cls == 2) ? 0.f : Whh_s[(k - 32) * 192 + col];
        else if (k == 96) v = (cls == 3) ? 0.f : Us_s[col];
        else if (k == 97) v = (cls < 2) ? (Vs_s[col] + bhh[col]) : (cls == 2 ? Vs_s[col] : bhh[col]);
        else              v = 0.f;
        a01[h2] = v;
      }
      wsu[WS_FRG + fi * 256 + L * 4 + d] = f16pair(a01[0], a01[1]);
    }
  }
}

// ---- K3: sparse aggregation, 2 bt streams, depth-4 pipeline, 8 blocks/CU ----
#define AGG_STEP(d) { \
    float vv = pv[d]; \
    v4f t0 = pb0[d], t1 = pb1[d]; \
    float2 p = pl[row * 69 + k + 4 + d]; \
    int off = __float_as_int(p.x) + fo; \
    pv[d] = p.y; \
    pb0[d] = *(const v4f*)(xb0 + off); \
    pb1[d] = *(const v4f*)(xb1 + off); \
    acc0 += vv * t0; acc1 += vv * t1; }

__global__ void __launch_bounds__(256, 8)
k_agg(const float* __restrict__ x, float* __restrict__ ws) {
  __shared__ float2 pl[32 * 69];        // 17.7 KB
  int tid = threadIdx.x;
  int chunk = blockIdx.x & 15;          // 16 chunks of 2 bt; XCD = blockIdx%8 pins slices
  int mg = blockIdx.x >> 4;             // [0,128): 32-row group
  int row = tid >> 3, f4 = tid & 7;
  int m = mg * 32 + row;
  const int* deg = (const int*)&ws[WS_DEG];
  const float2* pair = (const float2*)&ws[WS_PAIR];
  for (int qq = tid; qq < 32 * 68; qq += 256) {
    int r = qq / 68, sl = qq - r * 68;
    pl[r * 69 + sl] = pair[(size_t)(mg * 32 + r) * CAP_ + sl];
  }
  __syncthreads();
  int d0 = deg[m];
  int dm = min(d0, 64);
  int bound = dm;                       // wave-uniform max over the wave's 8 rows
  bound = max(bound, __shfl_xor(bound, 8, 64));
  bound = max(bound, __shfl_xor(bound, 16, 64));
  bound = max(bound, __shfl_xor(bound, 32, 64));
  bound = (bound + 3) & ~3;             // mult of 4; slots < 68 valid/zeroed
  int bt0 = chunk * 2;
  const float* xb0 = x + (size_t)bt0 * N_ * F_;
  const float* xb1 = xb0 + N_ * F_;
  int fo = f4 * 4;
  v4f acc0 = {0,0,0,0}, acc1 = {0,0,0,0};
  v4f pb0[4], pb1[4];
  float pv[4];
#pragma unroll
  for (int d = 0; d < 4; d++) {         // prologue: 8 loads in flight
    float2 p = pl[row * 69 + d];
    int off = __float_as_int(p.x) + fo;
    pv[d] = p.y;
    pb0[d] = *(const v4f*)(xb0 + off);
    pb1[d] = *(const v4f*)(xb1 + off);
  }
  for (int k = 0; k < bound; k += 4) {
    AGG_STEP(0) AGG_STEP(1) AGG_STEP(2) AGG_STEP(3)
  }
  if (d0 > 64) {                        // statistically never (avg deg ~32)
    for (int k = 64; k < d0; k++) {
      float2 p = pair[(size_t)m * CAP_ + k];
      int off = __float_as_int(p.x) + fo;
      float vv = p.y;
      acc0 += vv * *(const v4f*)(xb0 + off);
      acc1 += vv * *(const v4f*)(xb1 + off);
    }
  }
  size_t ob = (size_t)bt0 * N_ * F_ + m * F_ + fo;
  *(v4f*)(ws + WS_XA + ob) = acc0;
  *(v4f*)(ws + WS_XA + ob + (size_t)N_ * F_) = acc1;
}

// ---- K4: MFMA GRU; frg block-copied from ws ----
#define LDA(fi) (*(const half8*)(frg + (fi)*256 + L*4))
#define DO1(mt, fi, BH, BL) { half8 af = LDA(fi); \
  acc[mt] = __builtin_amdgcn_mfma_f32_16x16x32_f16(af, BH, acc[mt], 0, 0, 0); \
  acc[mt] = __builtin_amdgcn_mfma_f32_16x16x32_f16(af, BL, acc[mt], 0, 0, 0); }

__global__ void __launch_bounds__(256, 1)
k_gru(const float* __restrict__ Wd, const float* __restrict__ bd,
      const float* __restrict__ ws, float* __restrict__ out) {
  __shared__ uint32_t frg[52 * 256];     // 53 KB weight fragments
  __shared__ uint32_t hx[4 * 1344];      // per-wave h-exchange, stride 21
  {
    const uint4* gf = (const uint4*)(ws + WS_FRG);
    uint4* sf = (uint4*)frg;
    for (int i = threadIdx.x; i < 52 * 64; i += 256) sf[i] = gf[i];
  }
  __syncthreads();
  int wid = threadIdx.x >> 6, L = threadIdx.x & 63;
  int q = L >> 4, c = L & 15;
  uint32_t* hxw = hx + wid * 1344;
  int row0 = blockIdx.x * 64 + wid * 16;
  int b = row0 >> 12;
  int nb = row0 & (N_ - 1);
  float wdv[4][4];
#pragma unroll
  for (int g = 0; g < 4; g++)
#pragma unroll
    for (int r = 0; r < 4; r++) wdv[g][r] = Wd[16 * g + 4 * q + r];
  float bdv = bd[0];
  HU b3h, b3l;
#pragma unroll
  for (int d = 0; d < 4; d++) { b3h.u[d] = 0; b3l.u[d] = 0; }
  {
    float rsv = ws[WS_ROWSUM + nb + c];
    uint32_t rhi, rlo;
    sp2(rsv, 1.0f, rhi, rlo);
    if (q == 0) { b3h.u[0] = rhi; b3l.u[0] = rlo & 0xFFFFu; }
  }
  float h[4][4];
#pragma unroll
  for (int g = 0; g < 4; g++)
#pragma unroll
    for (int r = 0; r < 4; r++) h[g][r] = 0.f;

  const float* xab = ws + WS_XA;
  size_t xo0 = ((size_t)(b * T_) * N_ + nb + c) * F_ + q * 8;
  float4 xaA = *(const float4*)(xab + xo0);
  float4 xaB = *(const float4*)(xab + xo0 + 4);

  for (int t = 0; t < T_; t++) {
    float4 nxA, nxB;
    if (t < T_ - 1) {
      size_t xo = ((size_t)(b * T_ + t + 1) * N_ + nb + c) * F_ + q * 8;
      nxA = *(const float4*)(xab + xo);
      nxB = *(const float4*)(xab + xo + 4);
    }
#pragma unroll
    for (int g = 0; g < 4; g++)
#pragma unroll
      for (int rp = 0; rp < 2; rp++) {
        uint32_t phi, plo;
        sp2(h[g][2 * rp], h[g][2 * rp + 1], phi, plo);
        int pidx = 8 * g + 2 * q + rp;
        hxw[(pidx * 2 + 0) * 21 + c] = phi;
        hxw[(pidx * 2 + 1) * 21 + c] = plo;
      }
    HU b1h, b1l, b2h, b2l;
#pragma unroll
    for (int d = 0; d < 4; d++) {
      b1h.u[d] = hxw[((4 * q + d) * 2 + 0) * 21 + c];
      b1l.u[d] = hxw[((4 * q + d) * 2 + 1) * 21 + c];
      b2h.u[d] = hxw[((16 + 4 * q + d) * 2 + 0) * 21 + c];
      b2l.u[d] = hxw[((16 + 4 * q + d) * 2 + 1) * 21 + c];
    }
    v4f acc[16];
#pragma unroll
    for (int i = 0; i < 16; i++) acc[i] = (v4f){0.f, 0.f, 0.f, 0.f};
    DO1(0,1,b1h.v,b1l.v)  DO1(1,5,b1h.v,b1l.v)  DO1(2,9,b1h.v,b1l.v)  DO1(3,13,b1h.v,b1l.v)
    DO1(4,17,b1h.v,b1l.v) DO1(5,21,b1h.v,b1l.v) DO1(6,25,b1h.v,b1l.v) DO1(7,29,b1h.v,b1l.v)
    DO1(12,40,b1h.v,b1l.v) DO1(13,43,b1h.v,b1l.v) DO1(14,46,b1h.v,b1l.v) DO1(15,49,b1h.v,b1l.v)
    DO1(0,2,b2h.v,b2l.v)  DO1(1,6,b2h.v,b2l.v)  DO1(2,10,b2h.v,b2l.v) DO1(3,14,b2h.v,b2l.v)
    DO1(4,18,b2h.v,b2l.v) DO1(5,22,b2h.v,b2l.v) DO1(6,26,b2h.v,b2l.v) DO1(7,30,b2h.v,b2l.v)
    DO1(12,41,b2h.v,b2l.v) DO1(13,44,b2h.v,b2l.v) DO1(14,47,b2h.v,b2l.v) DO1(15,50,b2h.v,b2l.v)
    DO1(0,3,b3h.v,b3l.v)  DO1(1,7,b3h.v,b3l.v)  DO1(2,11,b3h.v,b3l.v) DO1(3,15,b3h.v,b3l.v)
    DO1(4,19,b3h.v,b3l.v) DO1(5,23,b3h.v,b3l.v) DO1(6,27,b3h.v,b3l.v) DO1(7,31,b3h.v,b3l.v)
    DO1(8,33,b3h.v,b3l.v) DO1(9,35,b3h.v,b3l.v) DO1(10,37,b3h.v,b3l.v) DO1(11,39,b3h.v,b3l.v)
    DO1(12,42,b3h.v,b3l.v) DO1(13,45,b3h.v,b3l.v) DO1(14,48,b3h.v,b3l.v) DO1(15,51,b3h.v,b3l.v)
    HU b0h, b0l;
    sp2(xaA.x, xaA.y, b0h.u[0], b0l.u[0]);
    sp2(xaA.z, xaA.w, b0h.u[1], b0l.u[1]);
    sp2(xaB.x, xaB.y, b0h.u[2], b0l.u[2]);
    sp2(xaB.z, xaB.w, b0h.u[3], b0l.u[3]);
    DO1(0,0,b0h.v,b0l.v)  DO1(1,4,b0h.v,b0l.v)  DO1(2,8,b0h.v,b0l.v)  DO1(3,12,b0h.v,b0l.v)
    DO1(4,16,b0h.v,b0l.v) DO1(5,20,b0h.v,b0l.v) DO1(6,24,b0h.v,b0l.v) DO1(7,28,b0h.v,b0l.v)
    DO1(8,32,b0h.v,b0l.v) DO1(9,34,b0h.v,b0l.v) DO1(10,36,b0h.v,b0l.v) DO1(11,38,b0h.v,b0l.v)
    float o = 0.f;
#pragma unroll
    for (int g = 0; g < 4; g++)
#pragma unroll
      for (int r = 0; r < 4; r++) {
        float rr = sigm_f(acc[g][r]);
        float z  = sigm_f(acc[4 + g][r]);
        float nn = 2.0f * sigm_f(2.0f * (acc[8 + g][r] + rr * acc[12 + g][r])) - 1.0f;
        float hn = z * (h[g][r] - nn) + nn;
        h[g][r] = hn;
        o += wdv[g][r] * hn;
      }
    o += __shfl_xor(o, 16, 64);
    o += __shfl_xor(o, 32, 64);
    if (L < 16) out[(size_t)(b * T_ + t) * N_ + nb + L] = o + bdv;
    xaA = nxA; xaB = nxB;
  }
}

extern "C" void kernel_launch(void* const* d_in, const int* in_sizes, int n_in,
                              void* d_out, int out_size, void* d_ws, size_t ws_size,
                              hipStream_t stream) {
  const float* x     = (const float*)d_in[0];
  const float* adj   = (const float*)d_in[1];
  const float* gamma = (const float*)d_in[2];
  const float* beta  = (const float*)d_in[3];
  const float* Wg    = (const float*)d_in[4];
  const float* bg    = (const float*)d_in[5];
  const float* Wih   = (const float*)d_in[6];
  const float* Whh   = (const float*)d_in[7];
  const float* bih   = (const float*)d_in[8];
  const float* bhh   = (const float*)d_in[9];
  const float* Wd    = (const float*)d_in[10];
  const float* bd    = (const float*)d_in[11];
  float* ws = (float*)d_ws;
  float* out = (float*)d_out;

  k_pre<<<2048 + 256, 256, 0, stream>>>(x, adj, ws);
  k_fold<<<1, 256, 0, stream>>>(gamma, beta, Wg, bg, Wih, bih, Whh, bhh, ws);
  k_agg<<<2048, 256, 0, stream>>>(x, ws);
  k_gru<<<256, 256, 0, stream>>>(Wd, bd, ws, out);
}